// Round 8
// baseline (164.447 us; speedup 1.0000x reference)
//
#include <hip/hip_runtime.h>

// Problem constants (B=4, S=2048, D=1024, O=1024, C=8)
#define TOK   8192
#define DIM   1024
#define OUTD  1024
#define NCAT  8
#define BM    128
#define BN    128
#define BK    64
#define NKT   (DIM / BK)          // 16 K-tiles
#define MAX_MT 71                 // sum ceil(n_c/128) <= 8192/128 + 7 = 71
#define MPMAX (MAX_MT * BM)       // 9088 padded rows

typedef __attribute__((ext_vector_type(8))) __bf16 bf16x8;
typedef __attribute__((ext_vector_type(4))) float  f32x4;

#define GLP(p)  (const __attribute__((address_space(1))) unsigned int*)(p)
#define LDSP(p) (__attribute__((address_space(3))) unsigned int*)(p)

__device__ __forceinline__ unsigned short f2bf(float f) {
  unsigned u = __float_as_uint(f);
  u += 0x7fffu + ((u >> 16) & 1u);      // RNE
  return (unsigned short)(u >> 16);
}

// ---------------- K1: fused {W transpose+convert} + {token bucketing} -------
// blocks 0..2047: wt[c][o][d] bf16 from w[c][d][o] fp32 (64x64 tiles)
// block 2048:     ballot-based deterministic bucketing (4 waves x 2048 tokens)
__global__ __launch_bounds__(256) void k_prep(const float* __restrict__ w,
    const int* __restrict__ cid, unsigned short* __restrict__ wt,
    int* __restrict__ row_token, int* __restrict__ tile_c, int* __restrict__ tile_m) {
  int tid = threadIdx.x;
  if (blockIdx.x < 2048) {
    int b = blockIdx.x;
    int ot = b & 15, dt = (b >> 4) & 15, c = b >> 8;
    __shared__ unsigned short t[64][72];              // +8: rows stay 16B-aligned
    int i  = tid >> 2;
    int jg = tid & 3;
    const float* src = w + ((size_t)c << 20) + (size_t)(dt * 64 + i) * 1024 + ot * 64 + jg * 16;
    #pragma unroll
    for (int q = 0; q < 4; ++q) {
      float4 v = *(const float4*)(src + q * 4);
      t[jg * 16 + q * 4 + 0][i] = f2bf(v.x);
      t[jg * 16 + q * 4 + 1][i] = f2bf(v.y);
      t[jg * 16 + q * 4 + 2][i] = f2bf(v.z);
      t[jg * 16 + q * 4 + 3][i] = f2bf(v.w);
    }
    __syncthreads();
    unsigned short* dst = wt + ((size_t)c << 20) + (size_t)(ot * 64 + i) * 1024 + dt * 64 + jg * 16;
    uint4 a = *(const uint4*)&t[i][jg * 16];
    uint4 bq = *(const uint4*)&t[i][jg * 16 + 8];
    *(uint4*)dst = a;
    *(uint4*)(dst + 8) = bq;
    return;
  }

  // ---- build block: 4 waves x 2048 tokens each (proven in R5) ----
  __shared__ int wcnt[4][NCAT];
  __shared__ int wbase[4][NCAT];
  __shared__ int gbase[NCAT];
  int lane = tid & 63, wave = tid >> 6;
  int base = wave * 2048;

  int cs[32];
  #pragma unroll
  for (int it = 0; it < 32; ++it) cs[it] = cid[base + it * 64 + lane];
  int cnt_loc[NCAT];
  #pragma unroll
  for (int c = 0; c < NCAT; ++c) cnt_loc[c] = 0;
  #pragma unroll
  for (int it = 0; it < 32; ++it)
    #pragma unroll
    for (int c = 0; c < NCAT; ++c)
      cnt_loc[c] += __popcll(__ballot(cs[it] == c));
  if (lane == 0) {
    #pragma unroll
    for (int c = 0; c < NCAT; ++c) wcnt[wave][c] = cnt_loc[c];
  }
  __syncthreads();

  if (tid == 0) {
    int pr = 0, mt = 0;
    for (int c = 0; c < NCAT; ++c) {
      int tot = 0;
      for (int wv = 0; wv < 4; ++wv) { wbase[wv][c] = tot; tot += wcnt[wv][c]; }
      gbase[c] = pr;
      int nt = (tot + BM - 1) / BM;
      for (int i = 0; i < nt; ++i) { tile_c[mt] = c; tile_m[mt] = pr + i * BM; ++mt; }
      pr += nt * BM;
    }
    for (; mt < MAX_MT; ++mt) { tile_c[mt] = -1; tile_m[mt] = 0; }
  }
  __syncthreads();
  for (int r = tid; r < MPMAX; r += 256) row_token[r] = -1;
  __syncthreads();

  int run[NCAT];
  #pragma unroll
  for (int c = 0; c < NCAT; ++c) run[c] = gbase[c] + wbase[wave][c];
  unsigned long long lt = (lane == 63) ? ~0ull >> 1 : ((1ull << lane) - 1);
  #pragma unroll
  for (int it = 0; it < 32; ++it) {
    int c = cs[it];
    int pos = 0;
    #pragma unroll
    for (int cat = 0; cat < NCAT; ++cat) {
      unsigned long long m = __ballot(cs[it] == cat);
      if (cat == c) pos = run[cat] + __popcll(m & lt);
      run[cat] += __popcll(m);
    }
    row_token[pos] = base + it * 64 + lane;
  }
}

// ---------------- K2: x gather + fp32->bf16 convert into bucketed layout ----
__global__ __launch_bounds__(256) void k_gather(const float* __restrict__ x,
    const int* __restrict__ row_token, unsigned short* __restrict__ xg) {
  int idx = blockIdx.x * 256 + threadIdx.x;   // one thread per 8 elements
  int r  = idx >> 7;
  int e0 = (idx & 127) << 3;
  if (r >= MPMAX) return;
  int tok = row_token[r];
  union { unsigned short u[8]; uint4 v; } o;
  if (tok >= 0) {
    const float4* s = (const float4*)(x + (size_t)tok * DIM + e0);
    float4 a = s[0], b = s[1];
    o.u[0] = f2bf(a.x); o.u[1] = f2bf(a.y); o.u[2] = f2bf(a.z); o.u[3] = f2bf(a.w);
    o.u[4] = f2bf(b.x); o.u[5] = f2bf(b.y); o.u[6] = f2bf(b.z); o.u[7] = f2bf(b.w);
  } else {
    o.v = make_uint4(0u, 0u, 0u, 0u);
  }
  *(uint4*)(xg + (size_t)r * DIM + e0) = o.v;
}

// ---------------- K3: grouped GEMM, 8-wave phase-interleaved, BK=64 ---------
// 128x128 tile, 8 waves (2M x 4N, per-wave 64x32), double-buffered 64KB LDS,
// 2 phases per K-tile (one per 32-k slab), counted vmcnt(2), setprio on MFMA,
// r&7 granule swizzle both-sides (128B rows: banks are row-independent).
__global__ __launch_bounds__(512, 4) void k_gemm(const unsigned short* __restrict__ xg,
    const unsigned short* __restrict__ wt, const float* __restrict__ bias,
    const int* __restrict__ row_token, const int* __restrict__ tile_c,
    const int* __restrict__ tile_m, float* __restrict__ out) {
  // bijective XCD-chunked remap: grid 568 = 8 XCDs * 71, m-major chunks.
  int wg  = blockIdx.x;
  int lin = (wg & 7) * MAX_MT + (wg >> 3);
  int mt  = lin >> 3;
  int nt  = lin & 7;
  int c = tile_c[mt];
  if (c < 0) return;
  int m0 = tile_m[mt];
  int n0 = nt * BN;

  __shared__ unsigned short As[2][BM][BK];   // 2 x 16 KB
  __shared__ unsigned short Bs[2][BM][BK];   // 2 x 16 KB

  int tid  = threadIdx.x;                    // 0..511
  int lane = tid & 63;
  int wave = tid >> 6;                       // 0..7
  int wr = wave >> 2, wc = wave & 3;         // 2 x 4 waves; per-wave 64 x 32

  f32x4 acc[4][2];
  #pragma unroll
  for (int m = 0; m < 4; ++m)
    #pragma unroll
    for (int n = 0; n < 2; ++n) acc[m][n] = (f32x4){0.f, 0.f, 0.f, 0.f};

  const unsigned short* Ag = xg + (size_t)m0 * DIM;
  const unsigned short* Bg = wt + ((size_t)c << 20) + (size_t)n0 * DIM;

  // staging map: tile = 128 rows x 8 granules(16B); 1024 granules / 512 thr = 2
  // passes. LDS dest linear (gidx*16); global source granule = phys ^ (row&7).
  int row0 = tid >> 3,         gp0 = tid & 7;           // pass 0: gidx = tid
  int row1 = (512 + tid) >> 3, gp1 = tid & 7;           // pass 1: gidx = 512+tid
  int gl0 = (gp0 ^ (row0 & 7)) << 3;                    // src element offset
  int gl1 = (gp1 ^ (row1 & 7)) << 3;

  auto STAGE_A = [&](int b, int kt) {
    __builtin_amdgcn_global_load_lds(GLP(Ag + (size_t)row0 * DIM + kt + gl0),
                                     LDSP(&As[b][row0][gp0 << 3]), 16, 0, 0);
    __builtin_amdgcn_global_load_lds(GLP(Ag + (size_t)row1 * DIM + kt + gl1),
                                     LDSP(&As[b][row1][gp1 << 3]), 16, 0, 0);
  };
  auto STAGE_B = [&](int b, int kt) {
    __builtin_amdgcn_global_load_lds(GLP(Bg + (size_t)row0 * DIM + kt + gl0),
                                     LDSP(&Bs[b][row0][gp0 << 3]), 16, 0, 0);
    __builtin_amdgcn_global_load_lds(GLP(Bg + (size_t)row1 * DIM + kt + gl1),
                                     LDSP(&Bs[b][row1][gp1 << 3]), 16, 0, 0);
  };

  // frag read offsets: logical granule (s*4 + lane>>4), phys = ^ (row&7);
  // row&7 == lane&7 for all frag rows (bases are multiples of 8).
  int lr = lane & 15, lq = lane >> 4, l7 = lane & 7;
  int goff0 = ((0 + lq) ^ l7) << 3;          // slab 0 element offset
  int goff1 = ((4 + lq) ^ l7) << 3;          // slab 1
  int arow = wr * 64 + lr;                   // + m*16
  int brow = wc * 32 + lr;                   // + n*16

  // prologue: stage tile 0 into buf 0
  STAGE_A(0, 0);
  STAGE_B(0, 0);

  int cur = 0;
  for (int t = 0; t < NKT; ++t) {
    int ktn = (t + 1) * BK;
    bool pre = (t + 1 < NKT);

    // ---- phase 0 (k-slab 0) ----
    if (pre) STAGE_A(cur ^ 1, ktn);          // 2 loads into nxt
    if (pre) asm volatile("s_waitcnt vmcnt(2)" ::: "memory");
    else     asm volatile("s_waitcnt vmcnt(0)" ::: "memory");
    __builtin_amdgcn_s_barrier();            // tile t resident for all waves

    {
      bf16x8 af[4], bf[2];
      #pragma unroll
      for (int m = 0; m < 4; ++m)
        af[m] = *(const bf16x8*)&As[cur][arow + m * 16][goff0];
      #pragma unroll
      for (int n = 0; n < 2; ++n)
        bf[n] = *(const bf16x8*)&Bs[cur][brow + n * 16][goff0];
      __builtin_amdgcn_s_setprio(1);
      #pragma unroll
      for (int m = 0; m < 4; ++m)
        #pragma unroll
        for (int n = 0; n < 2; ++n)
          acc[m][n] = __builtin_amdgcn_mfma_f32_16x16x32_bf16(af[m], bf[n], acc[m][n], 0, 0, 0);
      __builtin_amdgcn_s_setprio(0);
    }
    asm volatile("s_waitcnt lgkmcnt(0)" ::: "memory");  // reads retired pre-barrier
    __builtin_amdgcn_s_barrier();

    // ---- phase 1 (k-slab 1) ----
    if (pre) STAGE_B(cur ^ 1, ktn);          // 2 loads into nxt
    {
      bf16x8 af[4], bf[2];
      #pragma unroll
      for (int m = 0; m < 4; ++m)
        af[m] = *(const bf16x8*)&As[cur][arow + m * 16][goff1];
      #pragma unroll
      for (int n = 0; n < 2; ++n)
        bf[n] = *(const bf16x8*)&Bs[cur][brow + n * 16][goff1];
      __builtin_amdgcn_s_setprio(1);
      #pragma unroll
      for (int m = 0; m < 4; ++m)
        #pragma unroll
        for (int n = 0; n < 2; ++n)
          acc[m][n] = __builtin_amdgcn_mfma_f32_16x16x32_bf16(af[m], bf[n], acc[m][n], 0, 0, 0);
      __builtin_amdgcn_s_setprio(0);
    }
    asm volatile("s_waitcnt lgkmcnt(0)" ::: "memory");
    __builtin_amdgcn_s_barrier();            // last read of cur retired; nxt-stage
    cur ^= 1;                                // of next iter may overwrite old cur
  }

  // ---- epilogue: bias + scatter C ----
  int col = lr;
  int rq  = lq << 2;
  float bv[2];
  #pragma unroll
  for (int n = 0; n < 2; ++n) bv[n] = bias[c * OUTD + n0 + wc * 32 + n * 16 + col];
  #pragma unroll
  for (int m = 0; m < 4; ++m) {
    #pragma unroll
    for (int r = 0; r < 4; ++r) {
      int prow = m0 + wr * 64 + m * 16 + rq + r;
      int tok = row_token[prow];
      if (tok < 0) continue;
      float* orow = out + (size_t)tok * OUTD + n0 + wc * 32 + col;
      #pragma unroll
      for (int n = 0; n < 2; ++n) orow[n * 16] = acc[m][n][r] + bv[n];
    }
  }
}

// ---------------- launcher -------------------------------------------------
extern "C" void kernel_launch(void* const* d_in, const int* in_sizes, int n_in,
                              void* d_out, int out_size, void* d_ws, size_t ws_size,
                              hipStream_t stream) {
  const float* x    = (const float*)d_in[0];
  const int*   cid  = (const int*)d_in[1];
  const float* w    = (const float*)d_in[2];
  const float* bias = (const float*)d_in[3];
  float* out = (float*)d_out;

  char* ws = (char*)d_ws;
  constexpr size_t XG_BYTES = (size_t)MPMAX * DIM * 2;          // 18,612,224
  constexpr size_t WT_BYTES = (size_t)NCAT * DIM * OUTD * 2;    // 16,777,216
  constexpr size_t RT_BYTES = (size_t)MPMAX * 4;                // 36,352
  unsigned short* xg  = (unsigned short*)ws;
  unsigned short* wtb = (unsigned short*)(ws + XG_BYTES);
  int* row_token = (int*)(ws + XG_BYTES + WT_BYTES);
  int* tile_c    = (int*)(ws + XG_BYTES + WT_BYTES + RT_BYTES);
  int* tile_m    = tile_c + MAX_MT;

  // W transpose+convert (2048 blocks) + token bucketing (block 2048)
  k_prep<<<2049, 256, 0, stream>>>(w, cid, wtb, row_token, tile_c, tile_m);
  // x gather+convert (needs row_token)
  k_gather<<<(MPMAX * (DIM / 8) + 255) / 256, 256, 0, stream>>>(x, row_token, xg);
  // grouped GEMM
  k_gemm<<<8 * MAX_MT, 512, 0, stream>>>(xg, wtb, bias, row_token, tile_c, tile_m, out);
}